// Round 2
// baseline (186.481 us; speedup 1.0000x reference)
//
#include <hip/hip_runtime.h>
#include <hip/hip_bf16.h>
#include <hip/hip_fp16.h>

typedef __fp16 h2_t __attribute__((ext_vector_type(2)));
typedef unsigned int uint32;

#define S_DIM 8192
#define B_DIM 8192
#define Q_DIM 64
#define A_DIM 1024
#define H_DIM 64
#define N_GATES 576

#define MT 128        // rows per block tile
#define KC 1024       // K range per block (K-split = 8)
#define BK 32         // K step staged in LDS

__device__ __forceinline__ uint32 pk_f16(float x, float y) {
    h2_t h = __builtin_amdgcn_cvt_pkrtz(x, y);
    return __builtin_bit_cast(uint32, h);
}

__device__ __forceinline__ float dot2(uint32 a, uint32 b, float c) {
#if __has_builtin(__builtin_amdgcn_fdot2)
    return __builtin_amdgcn_fdot2(__builtin_bit_cast(h2_t, a),
                                  __builtin_bit_cast(h2_t, b), c, false);
#else
    h2_t ha = __builtin_bit_cast(h2_t, a);
    h2_t hb = __builtin_bit_cast(h2_t, b);
    return c + (float)ha.x * (float)hb.x + (float)ha.y * (float)hb.y;
#endif
}

// K1: logits[b][q] += state[b, k0:k0+KC] . enc_w[q, k0:k0+KC]  (f16 dot2 path)
__global__ __launch_bounds__(256, 2) void k_gemm(
        const float* __restrict__ state, const float* __restrict__ encw,
        float* __restrict__ logits) {
    // As[k2][g(m)] : half2 over k (pad 4 per 32 rows to spread banks, keep 16B align)
    __shared__ uint32 As[16][144];
    __shared__ uint32 Bs[16][64];
    const int t  = threadIdx.x;
    const int m0 = blockIdx.x * MT;
    const int k0 = blockIdx.y * KC;

    // staging: A: 128 rows x 32k -> thread t loads row (t>>1), 16 floats at col (t&1)*16
    const int alm = t >> 1;
    const int alk = (t & 1) * 16;
    // staging: B: 64 rows x 32k -> thread t loads row (t>>2), 8 floats at col (t&3)*8
    const int blm = t >> 2;
    const int blk = (t & 3) * 8;
    // compute: 16x16 thread grid, rm=8 x rn=4
    const int tm = (t & 15) * 8;
    const int tn = (t >> 4) * 4;
    const int gm = tm + ((tm >> 5) << 2);   // padded row index
    const int am = alm + ((alm >> 5) << 2);

    float acc[8][4] = {};

    const float* pa = state + (size_t)(m0 + alm) * S_DIM + k0 + alk;
    const float* pb = encw  + (size_t)blm       * S_DIM + k0 + blk;

    for (int kt = 0; kt < KC; kt += BK) {
        float4 a0 = *(const float4*)(pa + kt);
        float4 a1 = *(const float4*)(pa + kt + 4);
        float4 a2 = *(const float4*)(pa + kt + 8);
        float4 a3 = *(const float4*)(pa + kt + 12);
        float4 b0 = *(const float4*)(pb + kt);
        float4 b1 = *(const float4*)(pb + kt + 4);
        __syncthreads();   // previous tile's reads complete before overwrite
        const int ak2 = alk >> 1;
        As[ak2 + 0][am] = pk_f16(a0.x, a0.y);
        As[ak2 + 1][am] = pk_f16(a0.z, a0.w);
        As[ak2 + 2][am] = pk_f16(a1.x, a1.y);
        As[ak2 + 3][am] = pk_f16(a1.z, a1.w);
        As[ak2 + 4][am] = pk_f16(a2.x, a2.y);
        As[ak2 + 5][am] = pk_f16(a2.z, a2.w);
        As[ak2 + 6][am] = pk_f16(a3.x, a3.y);
        As[ak2 + 7][am] = pk_f16(a3.z, a3.w);
        const int bk2 = blk >> 1;
        Bs[bk2 + 0][blm] = pk_f16(b0.x, b0.y);
        Bs[bk2 + 1][blm] = pk_f16(b0.z, b0.w);
        Bs[bk2 + 2][blm] = pk_f16(b1.x, b1.y);
        Bs[bk2 + 3][blm] = pk_f16(b1.z, b1.w);
        __syncthreads();
#pragma unroll
        for (int k2 = 0; k2 < 16; ++k2) {
            uint4 alo = *(const uint4*)&As[k2][gm];
            uint4 ahi = *(const uint4*)&As[k2][gm + 4];
            uint4 bb  = *(const uint4*)&Bs[k2][tn];
            uint32 av[8] = {alo.x, alo.y, alo.z, alo.w, ahi.x, ahi.y, ahi.z, ahi.w};
            uint32 bv[4] = {bb.x, bb.y, bb.z, bb.w};
#pragma unroll
            for (int i = 0; i < 8; ++i)
#pragma unroll
                for (int j = 0; j < 4; ++j)
                    acc[i][j] = dot2(av[i], bv[j], acc[i][j]);
        }
    }
#pragma unroll
    for (int i = 0; i < 8; ++i)
#pragma unroll
        for (int j = 0; j < 4; ++j)
            atomicAdd(&logits[(size_t)(m0 + tm + i) * Q_DIM + tn + j], acc[i][j]);
}

// K2: per-row softmax over Q=64, accumulate column sums
__global__ void k_softmax(const float* __restrict__ logits,
                          const float* __restrict__ encb,
                          float* __restrict__ colsum) {
    __shared__ float red[4][64];
    const int lane = threadIdx.x & 63;
    const int wv   = threadIdx.x >> 6;
    const float eb = encb[lane];
    float accq = 0.f;
    for (int i = 0; i < 8; ++i) {
        const int r = blockIdx.x * 32 + i * 4 + wv;
        float x = logits[(size_t)r * Q_DIM + lane] + eb;
        float m = x;
        for (int o = 32; o > 0; o >>= 1) m = fmaxf(m, __shfl_xor(m, o));
        float e = __expf(x - m);
        float s = e;
        for (int o = 32; o > 0; o >>= 1) s += __shfl_xor(s, o);
        accq += e / s;
    }
    red[wv][lane] = accq;
    __syncthreads();
    if (threadIdx.x < 64) {
        float v = red[0][lane] + red[1][lane] + red[2][lane] + red[3][lane];
        atomicAdd(&colsum[lane], v);
    }
}

// K3: 576 sequential linear gates on colsum (single wave, shfl chain)
__global__ void k_gates(const float* __restrict__ colsum,
                        const float* __restrict__ qp,
                        float* __restrict__ tvec) {
    __shared__ float cs[N_GATES], ss[N_GATES];
    const int lane = threadIdx.x;   // 64 threads
    for (int g = lane; g < N_GATES; g += 64) {
        float th = qp[g] * 0.5f;
        cs[g] = __cosf(th);
        ss[g] = __sinf(th);
    }
    __syncthreads();
    float t = colsum[lane];
    for (int g = 0; g < N_GATES; ++g) {
        float prev = __shfl(t, (lane + 63) & 63);   // t[q-1 mod 64]
        t = fmaf(cs[g], t, ss[g] * prev);
    }
    tvec[lane] = t;
}

// K4: meas[a] = sum_q tvec[q] * mo[a][q][0]
__global__ void k_meas(const float* __restrict__ tvec,
                       const float* __restrict__ mo,
                       float* __restrict__ meas) {
    const int lane = threadIdx.x & 63;
    const int wv   = threadIdx.x >> 6;
    const int a    = blockIdx.x * 4 + wv;
    float v = tvec[lane] * mo[(size_t)a * 128 + lane * 2];
    for (int o = 32; o > 0; o >>= 1) v += __shfl_xor(v, o);
    if (lane == 0) meas[a] = v;
}

// K5: h[j] = relu(sum_a meas[a]*w1[j][a] + b1[j])
__global__ void k_hidden(const float* __restrict__ meas,
                         const float* __restrict__ w1,
                         const float* __restrict__ b1,
                         float* __restrict__ h) {
    __shared__ float red[4];
    const int j = blockIdx.x;
    const int t = threadIdx.x;
    float v = 0.f;
    for (int c = 0; c < 4; ++c) {
        const int a = t + c * 256;
        v += meas[a] * w1[(size_t)j * A_DIM + a];
    }
    for (int o = 32; o > 0; o >>= 1) v += __shfl_xor(v, o);
    if ((t & 63) == 0) red[t >> 6] = v;
    __syncthreads();
    if (t == 0) {
        float s = red[0] + red[1] + red[2] + red[3] + b1[j];
        h[j] = fmaxf(s, 0.f);
    }
}

// K6: out[a] = sum_j h[j]*w2[a][j] + b2[a]
__global__ void k_out(const float* __restrict__ h,
                      const float* __restrict__ w2,
                      const float* __restrict__ b2,
                      float* __restrict__ out) {
    const int lane = threadIdx.x & 63;
    const int wv   = threadIdx.x >> 6;
    const int a    = blockIdx.x * 4 + wv;
    float v = h[lane] * w2[(size_t)a * H_DIM + lane];
    for (int o = 32; o > 0; o >>= 1) v += __shfl_xor(v, o);
    if (lane == 0) out[a] = v + b2[a];
}

extern "C" void kernel_launch(void* const* d_in, const int* in_sizes, int n_in,
                              void* d_out, int out_size, void* d_ws, size_t ws_size,
                              hipStream_t stream) {
    const float* state = (const float*)d_in[0];
    const float* encw  = (const float*)d_in[1];
    const float* encb  = (const float*)d_in[2];
    const float* qp    = (const float*)d_in[3];
    const float* mo    = (const float*)d_in[4];
    const float* w1    = (const float*)d_in[5];
    const float* b1    = (const float*)d_in[6];
    const float* w2    = (const float*)d_in[7];
    const float* b2    = (const float*)d_in[8];
    float* out = (float*)d_out;

    float* ws      = (float*)d_ws;
    float* colsum  = ws;            // 64
    float* tvec    = ws + 64;       // 64
    float* meas    = ws + 128;      // 1024
    float* h       = ws + 1152;     // 64
    float* logits  = ws + 4096;     // 8192*64 (2 MB)

    // zero the atomic targets (colsum + logits) each call
    (void)hipMemsetAsync(d_ws, 0, (size_t)(4096 + B_DIM * Q_DIM) * sizeof(float), stream);

    k_gemm<<<dim3(B_DIM / MT, S_DIM / KC), dim3(256), 0, stream>>>(state, encw, logits);
    k_softmax<<<dim3(256), dim3(256), 0, stream>>>(logits, encb, colsum);
    k_gates<<<dim3(1), dim3(64), 0, stream>>>(colsum, qp, tvec);
    k_meas<<<dim3(256), dim3(256), 0, stream>>>(tvec, mo, meas);
    k_hidden<<<dim3(64), dim3(256), 0, stream>>>(meas, w1, b1, h);
    k_out<<<dim3(256), dim3(256), 0, stream>>>(h, w2, b2, out);
}

// Round 3
// 109.137 us; speedup vs baseline: 1.7087x; 1.7087x over previous
//
#include <hip/hip_runtime.h>
#include <hip/hip_fp16.h>

typedef __fp16 h2_t __attribute__((ext_vector_type(2)));
typedef _Float16 f16x8 __attribute__((ext_vector_type(8)));
typedef float f32x4 __attribute__((ext_vector_type(4)));
typedef unsigned int uint32;

#define S_DIM 8192
#define B_DIM 8192
#define Q_DIM 64
#define A_DIM 1024
#define H_DIM 64
#define N_GATES 576

#define MT 64                  // rows per block
#define KSPLIT 8
#define KC (S_DIM / KSPLIT)    // 1024 k per block
#define BK 64                  // k per staged step
#define NSTEP (KC / BK)        // 16

__device__ __forceinline__ uint32 pk_f16(float x, float y) {
    h2_t h = __builtin_amdgcn_cvt_pkrtz(x, y);
    return __builtin_bit_cast(uint32, h);
}

__device__ __forceinline__ f32x4 mfma16(uint4 a, uint4 b, f32x4 c) {
    return __builtin_amdgcn_mfma_f32_16x16x32_f16(
        __builtin_bit_cast(f16x8, a), __builtin_bit_cast(f16x8, b), c, 0, 0, 0);
}

// Pack enc_w [64][8192] f32 -> MFMA B-fragment order f16:
// bpack[(kt*4 + nt)*64 + lane] = B[n = nt*16 + lane%16][k = kt*32 + (lane/16)*8 .. +8]
__global__ void k_packB(const float* __restrict__ encw, uint4* __restrict__ bpack) {
    const int gid  = blockIdx.x * 256 + threadIdx.x;   // 65536 total
    const int lane = gid & 63;
    const int nt   = (gid >> 6) & 3;
    const int kt   = gid >> 8;                          // 0..255
    const int n = nt * 16 + (lane & 15);
    const int k = kt * 32 + (lane >> 4) * 8;
    const float* p = encw + (size_t)n * S_DIM + k;
    float4 x0 = *(const float4*)p;
    float4 x1 = *(const float4*)(p + 4);
    uint4 r;
    r.x = pk_f16(x0.x, x0.y);
    r.y = pk_f16(x0.z, x0.w);
    r.z = pk_f16(x1.x, x1.y);
    r.w = pk_f16(x1.z, x1.w);
    bpack[gid] = r;
}

// K1: logits[m][n] += state[m, k-range] . enc_w[n, k-range] via f16 MFMA
__global__ __launch_bounds__(256, 4) void k_gemm(
        const float* __restrict__ state, const uint4* __restrict__ bpack,
        float* __restrict__ logits) {
    // A tile as f16 pairs: 64 rows x 72 f16 (pad 64->72: row stride 144B = 4 banks)
    __shared__ __align__(16) uint32 As[2][MT][36];
    const int t  = threadIdx.x;
    const int w  = t >> 6;          // wave 0..3 -> m-subtile
    const int l  = t & 63;
    const int m0 = blockIdx.x * MT;
    const int k0 = blockIdx.y * KC;

    // A staging: thread t loads row t/4, 16 consecutive floats at col (t%4)*16
    const int ar = t >> 2;
    const int ac = (t & 3) * 16;
    const float* pa = state + (size_t)(m0 + ar) * S_DIM + k0 + ac;

    // B fragments, pre-packed, L2-resident
    const uint4* pb = bpack + (size_t)(k0 >> 5) * 4 * 64 + l;

    // compute-side fragment coords
    const int frow = w * 16 + (l & 15);
    const int fc   = (l >> 4) * 4;      // uint32 col within a 32k tile (16 u32 wide)

    f32x4 acc[4] = {};

    float4 ra0, ra1, ra2, ra3;
#define LOADA(off) do { \
        const float* p_ = pa + (off); \
        ra0 = *(const float4*)(p_);      ra1 = *(const float4*)(p_ + 4); \
        ra2 = *(const float4*)(p_ + 8);  ra3 = *(const float4*)(p_ + 12); } while (0)

#define CVTWRITE(buf) do { \
        uint4 w0, w1; \
        w0.x = pk_f16(ra0.x, ra0.y); w0.y = pk_f16(ra0.z, ra0.w); \
        w0.z = pk_f16(ra1.x, ra1.y); w0.w = pk_f16(ra1.z, ra1.w); \
        w1.x = pk_f16(ra2.x, ra2.y); w1.y = pk_f16(ra2.z, ra2.w); \
        w1.z = pk_f16(ra3.x, ra3.y); w1.w = pk_f16(ra3.z, ra3.w); \
        *(uint4*)&As[buf][ar][ac >> 1]       = w0; \
        *(uint4*)&As[buf][ar][(ac >> 1) + 4] = w1; } while (0)

    LOADA(0);
    CVTWRITE(0);

    for (int s = 0; s < NSTEP; ++s) {
        const int cur = s & 1;
        if (s + 1 < NSTEP) LOADA((s + 1) * BK);     // prefetch next A step
        uint4 bf0[4], bf1[4];                        // B frags for this step (from L2)
#pragma unroll
        for (int nt = 0; nt < 4; ++nt) {
            bf0[nt] = pb[(size_t)((s * 2 + 0) * 4 + nt) * 64];
            bf1[nt] = pb[(size_t)((s * 2 + 1) * 4 + nt) * 64];
        }
        __syncthreads();                             // As[cur] writes visible
        uint4 af0 = *(const uint4*)&As[cur][frow][fc];
        uint4 af1 = *(const uint4*)&As[cur][frow][fc + 16];
#pragma unroll
        for (int nt = 0; nt < 4; ++nt) {
            acc[nt] = mfma16(af0, bf0[nt], acc[nt]);
            acc[nt] = mfma16(af1, bf1[nt], acc[nt]);
        }
        __syncthreads();                             // reads done before overwrite
        if (s + 1 < NSTEP) CVTWRITE(cur ^ 1);
    }

    // C/D: col = lane&15, row = (lane>>4)*4 + reg  (verified mapping)
    const int mr = m0 + w * 16 + (l >> 4) * 4;
    const int nc = l & 15;
#pragma unroll
    for (int nt = 0; nt < 4; ++nt)
#pragma unroll
        for (int r = 0; r < 4; ++r)
            atomicAdd(&logits[(size_t)(mr + r) * Q_DIM + nt * 16 + nc], acc[nt][r]);
#undef LOADA
#undef CVTWRITE
}

// K2: per-row softmax over Q=64, accumulate column sums
__global__ void k_softmax(const float* __restrict__ logits,
                          const float* __restrict__ encb,
                          float* __restrict__ colsum) {
    __shared__ float red[4][64];
    const int lane = threadIdx.x & 63;
    const int wv   = threadIdx.x >> 6;
    const float eb = encb[lane];
    float accq = 0.f;
    for (int i = 0; i < 8; ++i) {
        const int r = blockIdx.x * 32 + i * 4 + wv;
        float x = logits[(size_t)r * Q_DIM + lane] + eb;
        float m = x;
        for (int o = 32; o > 0; o >>= 1) m = fmaxf(m, __shfl_xor(m, o));
        float e = __expf(x - m);
        float s = e;
        for (int o = 32; o > 0; o >>= 1) s += __shfl_xor(s, o);
        accq += e / s;
    }
    red[wv][lane] = accq;
    __syncthreads();
    if (threadIdx.x < 64) {
        float v = red[0][lane] + red[1][lane] + red[2][lane] + red[3][lane];
        atomicAdd(&colsum[lane], v);
    }
}

// K3: 576 sequential linear gates on colsum (single wave, shfl chain)
__global__ void k_gates(const float* __restrict__ colsum,
                        const float* __restrict__ qp,
                        float* __restrict__ tvec) {
    __shared__ float cs[N_GATES], ss[N_GATES];
    const int lane = threadIdx.x;   // 64 threads
    for (int g = lane; g < N_GATES; g += 64) {
        float th = qp[g] * 0.5f;
        cs[g] = __cosf(th);
        ss[g] = __sinf(th);
    }
    __syncthreads();
    float t = colsum[lane];
    for (int g = 0; g < N_GATES; ++g) {
        float prev = __shfl(t, (lane + 63) & 63);   // t[q-1 mod 64]
        t = fmaf(cs[g], t, ss[g] * prev);
    }
    tvec[lane] = t;
}

// K4: meas[a] = sum_q tvec[q] * mo[a][q][0]
__global__ void k_meas(const float* __restrict__ tvec,
                       const float* __restrict__ mo,
                       float* __restrict__ meas) {
    const int lane = threadIdx.x & 63;
    const int wv   = threadIdx.x >> 6;
    const int a    = blockIdx.x * 4 + wv;
    float v = tvec[lane] * mo[(size_t)a * 128 + lane * 2];
    for (int o = 32; o > 0; o >>= 1) v += __shfl_xor(v, o);
    if (lane == 0) meas[a] = v;
}

// K5: h[j] = relu(sum_a meas[a]*w1[j][a] + b1[j])
__global__ void k_hidden(const float* __restrict__ meas,
                         const float* __restrict__ w1,
                         const float* __restrict__ b1,
                         float* __restrict__ h) {
    __shared__ float red[4];
    const int j = blockIdx.x;
    const int t = threadIdx.x;
    float v = 0.f;
    for (int c = 0; c < 4; ++c) {
        const int a = t + c * 256;
        v += meas[a] * w1[(size_t)j * A_DIM + a];
    }
    for (int o = 32; o > 0; o >>= 1) v += __shfl_xor(v, o);
    if ((t & 63) == 0) red[t >> 6] = v;
    __syncthreads();
    if (t == 0) {
        float s = red[0] + red[1] + red[2] + red[3] + b1[j];
        h[j] = fmaxf(s, 0.f);
    }
}

// K6: out[a] = sum_j h[j]*w2[a][j] + b2[a]
__global__ void k_out(const float* __restrict__ h,
                      const float* __restrict__ w2,
                      const float* __restrict__ b2,
                      float* __restrict__ out) {
    const int lane = threadIdx.x & 63;
    const int wv   = threadIdx.x >> 6;
    const int a    = blockIdx.x * 4 + wv;
    float v = h[lane] * w2[(size_t)a * H_DIM + lane];
    for (int o = 32; o > 0; o >>= 1) v += __shfl_xor(v, o);
    if (lane == 0) out[a] = v + b2[a];
}

extern "C" void kernel_launch(void* const* d_in, const int* in_sizes, int n_in,
                              void* d_out, int out_size, void* d_ws, size_t ws_size,
                              hipStream_t stream) {
    const float* state = (const float*)d_in[0];
    const float* encw  = (const float*)d_in[1];
    const float* encb  = (const float*)d_in[2];
    const float* qp    = (const float*)d_in[3];
    const float* mo    = (const float*)d_in[4];
    const float* w1    = (const float*)d_in[5];
    const float* b1    = (const float*)d_in[6];
    const float* w2    = (const float*)d_in[7];
    const float* b2    = (const float*)d_in[8];
    float* out = (float*)d_out;

    float* ws      = (float*)d_ws;
    float* colsum  = ws;                    // 64
    float* tvec    = ws + 64;               // 64
    float* meas    = ws + 128;              // 1024
    float* h       = ws + 1152;             // 64
    float* logits  = ws + 4096;             // 8192*64 f32 (2 MB)
    uint4* bpack   = (uint4*)(ws + 4096 + B_DIM * Q_DIM);  // 65536 uint4 (1 MB)

    // zero atomic targets (colsum + logits)
    (void)hipMemsetAsync(d_ws, 0, (size_t)(4096 + B_DIM * Q_DIM) * sizeof(float), stream);

    k_packB<<<dim3(256), dim3(256), 0, stream>>>(encw, bpack);
    k_gemm<<<dim3(B_DIM / MT, KSPLIT), dim3(256), 0, stream>>>(state, bpack, logits);
    k_softmax<<<dim3(256), dim3(256), 0, stream>>>(logits, encb, colsum);
    k_gates<<<dim3(1), dim3(64), 0, stream>>>(colsum, qp, tvec);
    k_meas<<<dim3(256), dim3(256), 0, stream>>>(tvec, mo, meas);
    k_hidden<<<dim3(64), dim3(256), 0, stream>>>(meas, w1, b1, h);
    k_out<<<dim3(256), dim3(256), 0, stream>>>(h, w2, b2, out);
}